// Round 7
// baseline (1583.089 us; speedup 1.0000x reference)
//
#include <hip/hip_runtime.h>
#include <hip/hip_bf16.h>

#define N_TOK 4096
#define DIM   1024
#define VOCAB 32000
#define BM 128
#define BN 128
#define BKB 128         // K-bytes per stage = 128 fp8 elems = one 16x16x128 MFMA k-step
#define SMOOTH 0.1f
#define WSCALE 32.0f    // W quantized as W*32 (avoids e4m3 subnormal hole); B-scale = 2^-5

typedef __attribute__((ext_vector_type(8))) int   int8v;
typedef __attribute__((ext_vector_type(4))) int   int4v;
typedef __attribute__((ext_vector_type(4))) float float4v;

// E8M0 scales: all 4 bytes identical -> opsel-invariant, uniform across k-blocks
#define SCALE_ONE   0x7F7F7F7F   // 2^0
#define SCALE_W     0x7A7A7A7A   // 2^-5

// f32 -> fp8 e4m3 (OCP, saturating) for BOTH tensors in one dispatch.
// X stored as-is (sigma=1, normal range); W stored *32.
__global__ void cvt_fp8_2(const float* __restrict__ a, unsigned int* __restrict__ da, int n4a,
                          const float* __restrict__ b, unsigned int* __restrict__ db, int n4b) {
  int i = blockIdx.x * blockDim.x + threadIdx.x;
  const float4* s; unsigned int* d; int j; float sc;
  if (i < n4a)            { s = (const float4*)a; d = da; j = i;       sc = 1.0f;   }
  else if (i < n4a + n4b) { s = (const float4*)b; d = db; j = i - n4a; sc = WSCALE; }
  else return;
  float4 v = s[j];
  int p = 0;
  p = __builtin_amdgcn_cvt_pk_fp8_f32(v.x * sc, v.y * sc, p, false);  // bytes 0,1
  p = __builtin_amdgcn_cvt_pk_fp8_f32(v.z * sc, v.w * sc, p, true);   // bytes 2,3
  d[j] = (unsigned int)p;
}

__device__ __forceinline__ void gload_lds16(const unsigned char* g, unsigned char* l) {
  __builtin_amdgcn_global_load_lds((const __attribute__((address_space(1))) unsigned int*)g,
                                   (__attribute__((address_space(3))) unsigned int*)l,
                                   16, 0, 0);
}

// logit[n, y_n] in exact f32: one wave per token row (0.9-weighted term stays exact).
__global__ __launch_bounds__(256)
void tgt_dot(const float* __restrict__ x, const float* __restrict__ W,
             const int* __restrict__ y, float* __restrict__ tgtRow) {
  const int n = blockIdx.x * 4 + (threadIdx.x >> 6);
  const int lane = threadIdx.x & 63;
  const float4* xr = (const float4*)(x + (size_t)n * DIM);
  const float4* wr = (const float4*)(W + (size_t)y[n] * DIM);
  float d = 0.f;
#pragma unroll
  for (int i = 0; i < 4; ++i) {
    float4 a = xr[lane + 64 * i], b = wr[lane + 64 * i];
    d += a.x * b.x + a.y * b.y + a.z * b.z + a.w * b.w;
  }
#pragma unroll
  for (int off = 32; off > 0; off >>= 1) d += __shfl_xor(d, off, 64);
  if (lane == 0) tgtRow[n] = d;
}

// C = X * W^T in MX-fp8 (mfma_scale 16x16x128, A-scale 1, B-scale 2^-5) with
// fused per-row sum(exp) / sum. 128x128 tile, 4 waves 2x2, 8 K-iters.
// XOR-swizzled LDS (R4-verified 0-conflict).
// amdgpu_waves_per_eu(3,3): pin allocator to a 170-VGPR budget. R5/R6 showed
// the occupancy heuristic squeezing to 84 VGPR (=512/6, 6 waves/EU) and
// spilling ~1.3 KB/thread -> 5.3 GB scratch round-trip = entire runtime.
__global__ __launch_bounds__(256) __attribute__((amdgpu_waves_per_eu(3, 3)))
void gemm_ce(const unsigned char* __restrict__ Xf8, const unsigned char* __restrict__ Wf8,
             float* __restrict__ rowExp, float* __restrict__ rowSum) {
  __shared__ __align__(16) unsigned char As[BM * BKB];  // 16 KB
  __shared__ __align__(16) unsigned char Bs[BN * BKB];  // 16 KB

  const int ib = blockIdx.x;   // token tile (32) fastest: XCD = ib%8 (W reuse per XCD)
  const int jb = blockIdx.y;   // vocab tile (250)
  const int row0 = ib * BM;
  const int col0 = jb * BN;

  const int tid  = threadIdx.x;
  const int wv   = tid >> 6;
  const int lane = tid & 63;
  const int wr = wv >> 1, wc = wv & 1;
  const int quad = lane >> 4;
  const int r16  = lane & 15;
  // staging: 1 KB per inst = 8 rows x 8 colblocks(16B); LDS slot fixed at
  // base+lane*16; lane FETCHES global colblock (lane&7)^(lrow&7).
  const int lrow = lane >> 3;
  const int gcb  = (lane & 7) ^ (lrow & 7);
  const int r8   = r16 & 7;

  float4v acc[4][4];
#pragma unroll
  for (int i = 0; i < 4; ++i)
#pragma unroll
    for (int j = 0; j < 4; ++j) acc[i][j] = (float4v){0.f, 0.f, 0.f, 0.f};

  const int cbLo = ((quad * 2)     ^ r8) << 4;   // LDS byte offset of k-half 0
  const int cbHi = ((quad * 2 + 1) ^ r8) << 4;   // k-half 1

  for (int kk = 0; kk < DIM; kk += BKB) {
    __syncthreads();   // prior ds_reads done before overwrite
#pragma unroll
    for (int c = 0; c < 4; ++c) {
      const int rA = wv * 32 + c * 8;   // wave-uniform 8-row slab base
      gload_lds16(Xf8 + (size_t)(row0 + rA + lrow) * DIM + kk + gcb * 16, &As[rA * BKB]);
      gload_lds16(Wf8 + (size_t)(col0 + rA + lrow) * DIM + kk + gcb * 16, &Bs[rA * BKB]);
    }
    __syncthreads();   // staging visible (vmcnt drain)

    int8v bf[4];
#pragma unroll
    for (int j = 0; j < 4; ++j) {
      const int rowB = (wc * 64 + j * 16 + r16) * BKB;
      const int4v lo = *(const int4v*)&Bs[rowB + cbLo];
      const int4v hi = *(const int4v*)&Bs[rowB + cbHi];
      bf[j] = __builtin_shufflevector(lo, hi, 0, 1, 2, 3, 4, 5, 6, 7);
    }
#pragma unroll
    for (int i = 0; i < 4; ++i) {
      const int rowA = (wr * 64 + i * 16 + r16) * BKB;
      const int4v lo = *(const int4v*)&As[rowA + cbLo];
      const int4v hi = *(const int4v*)&As[rowA + cbHi];
      const int8v af = __builtin_shufflevector(lo, hi, 0, 1, 2, 3, 4, 5, 6, 7);
#pragma unroll
      for (int j = 0; j < 4; ++j)
        acc[i][j] = __builtin_amdgcn_mfma_scale_f32_16x16x128_f8f6f4(
            af, bf[j], acc[i][j],
            0, 0,                 // cbsz=fp8(e4m3), blgp=fp8(e4m3)
            0, SCALE_ONE,         // A scale 2^0
            0, SCALE_W);          // B scale 2^-5 (undoes W*32)
    }
  }

  // Fused epilogue: per-row sum(exp(logit)), sum(logit).
  // C/D layout (shape-determined): col = r16, row = quad*4 + reg
#pragma unroll
  for (int i = 0; i < 4; ++i)
#pragma unroll
    for (int r = 0; r < 4; ++r) {
      float se = 0.f, ss = 0.f;
#pragma unroll
      for (int j = 0; j < 4; ++j) {
        const float v = acc[i][j][r];
        ss += v;
        se += __expf(v);
      }
#pragma unroll
      for (int off = 1; off < 16; off <<= 1) {
        se += __shfl_xor(se, off, 64);
        ss += __shfl_xor(ss, off, 64);
      }
      if (r16 == 0) {
        const int rloc = wr * 64 + i * 16 + quad * 4 + r;
        atomicAdd(&rowExp[row0 + rloc], se);
        atomicAdd(&rowSum[row0 + rloc], ss);
      }
    }
}

// loss = (1/N) sum lse - (1-s)/N * sum tgt - s/(N*V) * sum(all logits)
__global__ void finalize_kernel(const float* __restrict__ rowExp, const float* __restrict__ rowSum,
                                const float* __restrict__ tgtRow, float* __restrict__ out) {
  __shared__ float s1[256], s2[256], s3[256];
  const int t = threadIdx.x;
  float a = 0.f, b = 0.f, c = 0.f;
  for (int n = t; n < N_TOK; n += 256) {
    a += logf(rowExp[n]);
    b += rowSum[n];
    c += tgtRow[n];
  }
  s1[t] = a; s2[t] = b; s3[t] = c;
  __syncthreads();
  for (int o = 128; o > 0; o >>= 1) {
    if (t < o) { s1[t] += s1[t + o]; s2[t] += s2[t + o]; s3[t] += s3[t + o]; }
    __syncthreads();
  }
  if (t == 0) {
    const float inviN = 1.0f / (float)N_TOK;
    out[0] = s1[0] * inviN
           - (1.0f - SMOOTH) * s3[0] * inviN
           - SMOOTH * s2[0] / ((float)N_TOK * (float)VOCAB);
  }
}

extern "C" void kernel_launch(void* const* d_in, const int* in_sizes, int n_in,
                              void* d_out, int out_size, void* d_ws, size_t ws_size,
                              hipStream_t stream) {
  const float* x = (const float*)d_in[0];
  const float* W = (const float*)d_in[1];
  const int*   y = (const int*)d_in[2];
  float* out = (float*)d_out;

  char* ws = (char*)d_ws;
  float* rowExp = (float*)(ws);              // 4096 f32
  float* rowSum = (float*)(ws + 16384);      // 4096 f32
  float* tgtRow = (float*)(ws + 32768);      // 4096 f32 (fully written, no memset)
  unsigned char* Xf8 = (unsigned char*)(ws + 65536);                        // 4.19 MB
  unsigned char* Wf8 = (unsigned char*)(ws + 65536 + (size_t)N_TOK * DIM);  // 32.77 MB

  hipMemsetAsync(ws, 0, 32768, stream);  // zero rowExp/rowSum (ws poisoned 0xAA)

  tgt_dot<<<N_TOK / 4, 256, 0, stream>>>(x, W, y, tgtRow);

  const int n4x = N_TOK * DIM / 4, n4w = VOCAB * DIM / 4;
  cvt_fp8_2<<<(n4x + n4w + 255) / 256, 256, 0, stream>>>(x, (unsigned int*)Xf8, n4x,
                                                         W, (unsigned int*)Wf8, n4w);

  dim3 grid(N_TOK / BM, VOCAB / BN);  // (32, 250)
  gemm_ce<<<grid, 256, 0, stream>>>(Xf8, Wf8, rowExp, rowSum);

  finalize_kernel<<<1, 256, 0, stream>>>(rowExp, rowSum, tgtRow, out);
}

// Round 8
// 1579.305 us; speedup vs baseline: 1.0024x; 1.0024x over previous
//
#include <hip/hip_runtime.h>
#include <hip/hip_bf16.h>

#define N_TOK 4096
#define DIM   1024
#define VOCAB 32000
#define BM 128
#define BN 128
#define BKB 128         // K-bytes per stage = 128 fp8 elems = one 16x16x128 MFMA k-step
#define SMOOTH 0.1f
#define WSCALE 32.0f    // W quantized as W*32 (avoids e4m3 subnormal hole); B-scale = 2^-5

typedef __attribute__((ext_vector_type(8))) int   int8v;
typedef __attribute__((ext_vector_type(4))) int   int4v;
typedef __attribute__((ext_vector_type(4))) float float4v;

// E8M0 scales: all 4 bytes identical -> opsel-invariant, uniform across k-blocks
#define SCALE_ONE   0x7F7F7F7F   // 2^0
#define SCALE_W     0x7A7A7A7A   // 2^-5

// f32 -> fp8 e4m3 (OCP, saturating) for BOTH tensors in one dispatch.
__global__ void cvt_fp8_2(const float* __restrict__ a, unsigned int* __restrict__ da, int n4a,
                          const float* __restrict__ b, unsigned int* __restrict__ db, int n4b) {
  int i = blockIdx.x * blockDim.x + threadIdx.x;
  const float4* s; unsigned int* d; int j; float sc;
  if (i < n4a)            { s = (const float4*)a; d = da; j = i;       sc = 1.0f;   }
  else if (i < n4a + n4b) { s = (const float4*)b; d = db; j = i - n4a; sc = WSCALE; }
  else return;
  float4 v = s[j];
  int p = 0;
  p = __builtin_amdgcn_cvt_pk_fp8_f32(v.x * sc, v.y * sc, p, false);  // bytes 0,1
  p = __builtin_amdgcn_cvt_pk_fp8_f32(v.z * sc, v.w * sc, p, true);   // bytes 2,3
  d[j] = (unsigned int)p;
}

__device__ __forceinline__ void gload_lds16(const unsigned char* g, unsigned char* l) {
  __builtin_amdgcn_global_load_lds((const __attribute__((address_space(1))) unsigned int*)g,
                                   (__attribute__((address_space(3))) unsigned int*)l,
                                   16, 0, 0);
}

// logit[n, y_n] in exact f32: one wave per token row (0.9-weighted term stays exact).
__global__ __launch_bounds__(256)
void tgt_dot(const float* __restrict__ x, const float* __restrict__ W,
             const int* __restrict__ y, float* __restrict__ tgtRow) {
  const int n = blockIdx.x * 4 + (threadIdx.x >> 6);
  const int lane = threadIdx.x & 63;
  const float4* xr = (const float4*)(x + (size_t)n * DIM);
  const float4* wr = (const float4*)(W + (size_t)y[n] * DIM);
  float d = 0.f;
#pragma unroll
  for (int i = 0; i < 4; ++i) {
    float4 a = xr[lane + 64 * i], b = wr[lane + 64 * i];
    d += a.x * b.x + a.y * b.y + a.z * b.z + a.w * b.w;
  }
#pragma unroll
  for (int off = 32; off > 0; off >>= 1) d += __shfl_xor(d, off, 64);
  if (lane == 0) tgtRow[n] = d;
}

// C = X * W^T in MX-fp8 (mfma_scale 16x16x128) with fused per-row sum(exp)/sum.
// 128x128 tile, 4 waves 2x2, 8 K-iters, XOR-swizzled LDS (R4: 0 conflicts).
// ALL hot-path locals are named scalars/vectors -- R5-R7 showed the acc/bf
// ARRAYS demoted to scratch (2.66 GB spill writes, immune to occupancy
// attributes). No arrays => nothing can be demoted.
#define MFMA1(AF, J, ACC) \
  ACC = __builtin_amdgcn_mfma_scale_f32_16x16x128_f8f6f4(AF, bf##J, ACC, 0, 0, 0, SCALE_ONE, 0, SCALE_W);

#define LOADB(J) \
  int8v bf##J; { \
    const int rowB = (wc * 64 + J * 16 + r16) * BKB; \
    const int4v lo = *(const int4v*)&Bs[rowB + cbLo]; \
    const int4v hi = *(const int4v*)&Bs[rowB + cbHi]; \
    bf##J = __builtin_shufflevector(lo, hi, 0, 1, 2, 3, 4, 5, 6, 7); }

#define MFMA_ROW(I) { \
    const int rowA = (wr * 64 + I * 16 + r16) * BKB; \
    const int4v lo = *(const int4v*)&As[rowA + cbLo]; \
    const int4v hi = *(const int4v*)&As[rowA + cbHi]; \
    const int8v af = __builtin_shufflevector(lo, hi, 0, 1, 2, 3, 4, 5, 6, 7); \
    MFMA1(af, 0, acc##I##0) MFMA1(af, 1, acc##I##1) \
    MFMA1(af, 2, acc##I##2) MFMA1(af, 3, acc##I##3) }

#define EPIROW(I, R) { \
    float ss = acc##I##0[R] + acc##I##1[R] + acc##I##2[R] + acc##I##3[R]; \
    float se = __expf(acc##I##0[R]) + __expf(acc##I##1[R]) + \
               __expf(acc##I##2[R]) + __expf(acc##I##3[R]); \
    se += __shfl_xor(se, 1, 64);  ss += __shfl_xor(ss, 1, 64); \
    se += __shfl_xor(se, 2, 64);  ss += __shfl_xor(ss, 2, 64); \
    se += __shfl_xor(se, 4, 64);  ss += __shfl_xor(ss, 4, 64); \
    se += __shfl_xor(se, 8, 64);  ss += __shfl_xor(ss, 8, 64); \
    if (r16 == 0) { \
      const int rloc = wr * 64 + I * 16 + quad * 4 + R; \
      atomicAdd(&rowExp[row0 + rloc], se); \
      atomicAdd(&rowSum[row0 + rloc], ss); \
    } }

__global__ __launch_bounds__(256, 3)
void gemm_ce(const unsigned char* __restrict__ Xf8, const unsigned char* __restrict__ Wf8,
             float* __restrict__ rowExp, float* __restrict__ rowSum) {
  __shared__ __align__(16) unsigned char As[BM * BKB];  // 16 KB
  __shared__ __align__(16) unsigned char Bs[BN * BKB];  // 16 KB

  const int ib = blockIdx.x;   // token tile (32) fastest: XCD = ib%8 (W reuse per XCD)
  const int jb = blockIdx.y;   // vocab tile (250)
  const int row0 = ib * BM;
  const int col0 = jb * BN;

  const int tid  = threadIdx.x;
  const int wv   = tid >> 6;
  const int lane = tid & 63;
  const int wr = wv >> 1, wc = wv & 1;
  const int quad = lane >> 4;
  const int r16  = lane & 15;
  const int lrow = lane >> 3;
  const int gcb  = (lane & 7) ^ (lrow & 7);   // swizzled source colblock
  const int r8   = r16 & 7;

  const int cbLo = ((quad * 2)     ^ r8) << 4;   // LDS byte offset of k-half 0
  const int cbHi = ((quad * 2 + 1) ^ r8) << 4;   // k-half 1

  float4v acc00 = {0.f,0.f,0.f,0.f}, acc01 = {0.f,0.f,0.f,0.f},
          acc02 = {0.f,0.f,0.f,0.f}, acc03 = {0.f,0.f,0.f,0.f},
          acc10 = {0.f,0.f,0.f,0.f}, acc11 = {0.f,0.f,0.f,0.f},
          acc12 = {0.f,0.f,0.f,0.f}, acc13 = {0.f,0.f,0.f,0.f},
          acc20 = {0.f,0.f,0.f,0.f}, acc21 = {0.f,0.f,0.f,0.f},
          acc22 = {0.f,0.f,0.f,0.f}, acc23 = {0.f,0.f,0.f,0.f},
          acc30 = {0.f,0.f,0.f,0.f}, acc31 = {0.f,0.f,0.f,0.f},
          acc32 = {0.f,0.f,0.f,0.f}, acc33 = {0.f,0.f,0.f,0.f};

  for (int kk = 0; kk < DIM; kk += BKB) {
    __syncthreads();   // prior ds_reads done before overwrite
#pragma unroll
    for (int c = 0; c < 4; ++c) {
      const int rA = wv * 32 + c * 8;   // wave-uniform 8-row slab base
      gload_lds16(Xf8 + (size_t)(row0 + rA + lrow) * DIM + kk + gcb * 16, &As[rA * BKB]);
      gload_lds16(Wf8 + (size_t)(col0 + rA + lrow) * DIM + kk + gcb * 16, &Bs[rA * BKB]);
    }
    __syncthreads();   // staging visible (vmcnt drain)

    LOADB(0) LOADB(1) LOADB(2) LOADB(3)
    MFMA_ROW(0) MFMA_ROW(1) MFMA_ROW(2) MFMA_ROW(3)
  }

  // Fused epilogue. C/D layout (shape-determined): col = r16, row = quad*4 + reg
  EPIROW(0,0) EPIROW(0,1) EPIROW(0,2) EPIROW(0,3)
  EPIROW(1,0) EPIROW(1,1) EPIROW(1,2) EPIROW(1,3)
  EPIROW(2,0) EPIROW(2,1) EPIROW(2,2) EPIROW(2,3)
  EPIROW(3,0) EPIROW(3,1) EPIROW(3,2) EPIROW(3,3)
}

// loss = (1/N) sum lse - (1-s)/N * sum tgt - s/(N*V) * sum(all logits)
__global__ void finalize_kernel(const float* __restrict__ rowExp, const float* __restrict__ rowSum,
                                const float* __restrict__ tgtRow, float* __restrict__ out) {
  __shared__ float s1[256], s2[256], s3[256];
  const int t = threadIdx.x;
  float a = 0.f, b = 0.f, c = 0.f;
  for (int n = t; n < N_TOK; n += 256) {
    a += logf(rowExp[n]);
    b += rowSum[n];
    c += tgtRow[n];
  }
  s1[t] = a; s2[t] = b; s3[t] = c;
  __syncthreads();
  for (int o = 128; o > 0; o >>= 1) {
    if (t < o) { s1[t] += s1[t + o]; s2[t] += s2[t + o]; s3[t] += s3[t + o]; }
    __syncthreads();
  }
  if (t == 0) {
    const float inviN = 1.0f / (float)N_TOK;
    out[0] = s1[0] * inviN
           - (1.0f - SMOOTH) * s3[0] * inviN
           - SMOOTH * s2[0] / ((float)N_TOK * (float)VOCAB);
  }
}

extern "C" void kernel_launch(void* const* d_in, const int* in_sizes, int n_in,
                              void* d_out, int out_size, void* d_ws, size_t ws_size,
                              hipStream_t stream) {
  const float* x = (const float*)d_in[0];
  const float* W = (const float*)d_in[1];
  const int*   y = (const int*)d_in[2];
  float* out = (float*)d_out;

  char* ws = (char*)d_ws;
  float* rowExp = (float*)(ws);              // 4096 f32
  float* rowSum = (float*)(ws + 16384);      // 4096 f32
  float* tgtRow = (float*)(ws + 32768);      // 4096 f32 (fully written, no memset)
  unsigned char* Xf8 = (unsigned char*)(ws + 65536);                        // 4.19 MB
  unsigned char* Wf8 = (unsigned char*)(ws + 65536 + (size_t)N_TOK * DIM);  // 32.77 MB

  hipMemsetAsync(ws, 0, 32768, stream);  // zero rowExp/rowSum (ws poisoned 0xAA)

  tgt_dot<<<N_TOK / 4, 256, 0, stream>>>(x, W, y, tgtRow);

  const int n4x = N_TOK * DIM / 4, n4w = VOCAB * DIM / 4;
  cvt_fp8_2<<<(n4x + n4w + 255) / 256, 256, 0, stream>>>(x, (unsigned int*)Xf8, n4x,
                                                         W, (unsigned int*)Wf8, n4w);

  dim3 grid(N_TOK / BM, VOCAB / BN);  // (32, 250)
  gemm_ce<<<grid, 256, 0, stream>>>(Xf8, Wf8, rowExp, rowSum);

  finalize_kernel<<<1, 256, 0, stream>>>(rowExp, rowSum, tgtRow, out);
}

// Round 9
// 1473.017 us; speedup vs baseline: 1.0747x; 1.0722x over previous
//
#include <hip/hip_runtime.h>
#include <hip/hip_bf16.h>

#define N_TOK 4096
#define DIM   1024
#define VOCAB 32000
#define BM 128
#define BN 128
#define BKB 128         // K-bytes per stage = 128 fp8 elems = one 16x16x128 MFMA k-step
#define SMOOTH 0.1f
#define WSCALE 32.0f    // W quantized as W*32 (avoids e4m3 subnormal hole); B-scale = 2^-5

typedef __attribute__((ext_vector_type(8))) int   int8v;
typedef __attribute__((ext_vector_type(4))) float float4v;

// E8M0 scales: all 4 bytes identical -> opsel-invariant, uniform across k-blocks
#define SCALE_ONE   0x7F7F7F7F   // 2^0
#define SCALE_W     0x7A7A7A7A   // 2^-5

// f32 -> fp8 e4m3 (OCP, saturating) for BOTH tensors in one dispatch.
__global__ void cvt_fp8_2(const float* __restrict__ a, unsigned int* __restrict__ da, int n4a,
                          const float* __restrict__ b, unsigned int* __restrict__ db, int n4b) {
  int i = blockIdx.x * blockDim.x + threadIdx.x;
  const float4* s; unsigned int* d; int j; float sc;
  if (i < n4a)            { s = (const float4*)a; d = da; j = i;       sc = 1.0f;   }
  else if (i < n4a + n4b) { s = (const float4*)b; d = db; j = i - n4a; sc = WSCALE; }
  else return;
  float4 v = s[j];
  int p = 0;
  p = __builtin_amdgcn_cvt_pk_fp8_f32(v.x * sc, v.y * sc, p, false);  // bytes 0,1
  p = __builtin_amdgcn_cvt_pk_fp8_f32(v.z * sc, v.w * sc, p, true);   // bytes 2,3
  d[j] = (unsigned int)p;
}

__device__ __forceinline__ void gload_lds16(const unsigned char* g, unsigned char* l) {
  __builtin_amdgcn_global_load_lds((const __attribute__((address_space(1))) unsigned int*)g,
                                   (__attribute__((address_space(3))) unsigned int*)l,
                                   16, 0, 0);
}

// logit[n, y_n] in exact f32: one wave per token row (0.9-weighted term stays exact).
__global__ __launch_bounds__(256)
void tgt_dot(const float* __restrict__ x, const float* __restrict__ W,
             const int* __restrict__ y, float* __restrict__ tgtRow) {
  const int n = blockIdx.x * 4 + (threadIdx.x >> 6);
  const int lane = threadIdx.x & 63;
  const float4* xr = (const float4*)(x + (size_t)n * DIM);
  const float4* wr = (const float4*)(W + (size_t)y[n] * DIM);
  float d = 0.f;
#pragma unroll
  for (int i = 0; i < 4; ++i) {
    float4 a = xr[lane + 64 * i], b = wr[lane + 64 * i];
    d += a.x * b.x + a.y * b.y + a.z * b.z + a.w * b.w;
  }
#pragma unroll
  for (int off = 32; off > 0; off >>= 1) d += __shfl_xor(d, off, 64);
  if (lane == 0) tgtRow[n] = d;
}

// C = X * W^T in MX-fp8 (mfma_scale 16x16x128) with fused per-row sum(exp)/sum.
// 128x128 tile, 4 waves 2x2, 8 K-iters.
// FRAGMENTS: single direct 32-B v8 load from LDS. R5-R8's two-16B-load
// concatenation was lowered through scratch (WRITE_SIZE 2.62 GB = 5 frags x
// 32 B x threads x iters, immune to occupancy attrs / named scalars).
// SWIZZLE at 32-B granularity: LDS[row][b32] = G[row][b32 ^ (row&3)];
// reader block q ^ (r16&3) cancels to IDENTITY k-order for every lane
// (required: A[m,k] and B[n,k] are loaded by different lanes, so the
// k-permutation must be lane-invariant).
#define MFMA1(AF, J, ACC) \
  ACC = __builtin_amdgcn_mfma_scale_f32_16x16x128_f8f6f4(AF, bf##J, ACC, 0, 0, 0, SCALE_ONE, 0, SCALE_W);

#define LOADB(J) \
  const int8v bf##J = *(const int8v*)&Bs[(wc * 64 + J * 16 + r16) * BKB + cb32];

#define MFMA_ROW(I) { \
    const int8v af = *(const int8v*)&As[(wr * 64 + I * 16 + r16) * BKB + cb32]; \
    MFMA1(af, 0, acc##I##0) MFMA1(af, 1, acc##I##1) \
    MFMA1(af, 2, acc##I##2) MFMA1(af, 3, acc##I##3) }

#define EPIROW(I, R) { \
    float ss = acc##I##0[R] + acc##I##1[R] + acc##I##2[R] + acc##I##3[R]; \
    float se = __expf(acc##I##0[R]) + __expf(acc##I##1[R]) + \
               __expf(acc##I##2[R]) + __expf(acc##I##3[R]); \
    se += __shfl_xor(se, 1, 64);  ss += __shfl_xor(ss, 1, 64); \
    se += __shfl_xor(se, 2, 64);  ss += __shfl_xor(ss, 2, 64); \
    se += __shfl_xor(se, 4, 64);  ss += __shfl_xor(ss, 4, 64); \
    se += __shfl_xor(se, 8, 64);  ss += __shfl_xor(ss, 8, 64); \
    if (r16 == 0) { \
      const int rloc = wr * 64 + I * 16 + quad * 4 + R; \
      atomicAdd(&rowExp[row0 + rloc], se); \
      atomicAdd(&rowSum[row0 + rloc], ss); \
    } }

__global__ __launch_bounds__(256, 3)
void gemm_ce(const unsigned char* __restrict__ Xf8, const unsigned char* __restrict__ Wf8,
             float* __restrict__ rowExp, float* __restrict__ rowSum) {
  __shared__ __align__(32) unsigned char As[BM * BKB];  // 16 KB
  __shared__ __align__(32) unsigned char Bs[BN * BKB];  // 16 KB

  const int ib = blockIdx.x;   // token tile (32) fastest: XCD = ib%8 (W reuse per XCD)
  const int jb = blockIdx.y;   // vocab tile (250)
  const int row0 = ib * BM;
  const int col0 = jb * BN;

  const int tid  = threadIdx.x;
  const int wv   = tid >> 6;
  const int lane = tid & 63;
  const int wr = wv >> 1, wc = wv & 1;
  const int quad = lane >> 4;
  const int r16  = lane & 15;
  // staging: 1 KB per inst = 8 rows x 8 colblocks(16B); LDS slot fixed at
  // base+lane*16. Lane fetches the global 16B-colblock that the 32B-granule
  // swizzle demands:  g = ((slot32 ^ (lrow&3)) << 1) | half.
  const int lrow = lane >> 3;
  const int gcb  = ((((lane & 7) >> 1) ^ (lrow & 3)) << 1) | (lane & 1);
  // reader: 32B-block (quad ^ (row&3)); row&3 == r16&3 for all fragment rows
  const int cb32 = (quad ^ (r16 & 3)) << 5;

  float4v acc00 = {0.f,0.f,0.f,0.f}, acc01 = {0.f,0.f,0.f,0.f},
          acc02 = {0.f,0.f,0.f,0.f}, acc03 = {0.f,0.f,0.f,0.f},
          acc10 = {0.f,0.f,0.f,0.f}, acc11 = {0.f,0.f,0.f,0.f},
          acc12 = {0.f,0.f,0.f,0.f}, acc13 = {0.f,0.f,0.f,0.f},
          acc20 = {0.f,0.f,0.f,0.f}, acc21 = {0.f,0.f,0.f,0.f},
          acc22 = {0.f,0.f,0.f,0.f}, acc23 = {0.f,0.f,0.f,0.f},
          acc30 = {0.f,0.f,0.f,0.f}, acc31 = {0.f,0.f,0.f,0.f},
          acc32 = {0.f,0.f,0.f,0.f}, acc33 = {0.f,0.f,0.f,0.f};

  for (int kk = 0; kk < DIM; kk += BKB) {
    __syncthreads();   // prior ds_reads done before overwrite
#pragma unroll
    for (int c = 0; c < 4; ++c) {
      const int rA = wv * 32 + c * 8;   // wave-uniform 8-row slab base
      gload_lds16(Xf8 + (size_t)(row0 + rA + lrow) * DIM + kk + gcb * 16, &As[rA * BKB]);
      gload_lds16(Wf8 + (size_t)(col0 + rA + lrow) * DIM + kk + gcb * 16, &Bs[rA * BKB]);
    }
    __syncthreads();   // staging visible (vmcnt drain)

    LOADB(0) LOADB(1) LOADB(2) LOADB(3)
    MFMA_ROW(0) MFMA_ROW(1) MFMA_ROW(2) MFMA_ROW(3)
  }

  // Fused epilogue. C/D layout (shape-determined): col = r16, row = quad*4 + reg
  EPIROW(0,0) EPIROW(0,1) EPIROW(0,2) EPIROW(0,3)
  EPIROW(1,0) EPIROW(1,1) EPIROW(1,2) EPIROW(1,3)
  EPIROW(2,0) EPIROW(2,1) EPIROW(2,2) EPIROW(2,3)
  EPIROW(3,0) EPIROW(3,1) EPIROW(3,2) EPIROW(3,3)
}

// loss = (1/N) sum lse - (1-s)/N * sum tgt - s/(N*V) * sum(all logits)
__global__ void finalize_kernel(const float* __restrict__ rowExp, const float* __restrict__ rowSum,
                                const float* __restrict__ tgtRow, float* __restrict__ out) {
  __shared__ float s1[256], s2[256], s3[256];
  const int t = threadIdx.x;
  float a = 0.f, b = 0.f, c = 0.f;
  for (int n = t; n < N_TOK; n += 256) {
    a += logf(rowExp[n]);
    b += rowSum[n];
    c += tgtRow[n];
  }
  s1[t] = a; s2[t] = b; s3[t] = c;
  __syncthreads();
  for (int o = 128; o > 0; o >>= 1) {
    if (t < o) { s1[t] += s1[t + o]; s2[t] += s2[t + o]; s3[t] += s3[t + o]; }
    __syncthreads();
  }
  if (t == 0) {
    const float inviN = 1.0f / (float)N_TOK;
    out[0] = s1[0] * inviN
           - (1.0f - SMOOTH) * s3[0] * inviN
           - SMOOTH * s2[0] / ((float)N_TOK * (float)VOCAB);
  }
}

extern "C" void kernel_launch(void* const* d_in, const int* in_sizes, int n_in,
                              void* d_out, int out_size, void* d_ws, size_t ws_size,
                              hipStream_t stream) {
  const float* x = (const float*)d_in[0];
  const float* W = (const float*)d_in[1];
  const int*   y = (const int*)d_in[2];
  float* out = (float*)d_out;

  char* ws = (char*)d_ws;
  float* rowExp = (float*)(ws);              // 4096 f32
  float* rowSum = (float*)(ws + 16384);      // 4096 f32
  float* tgtRow = (float*)(ws + 32768);      // 4096 f32 (fully written, no memset)
  unsigned char* Xf8 = (unsigned char*)(ws + 65536);                        // 4.19 MB
  unsigned char* Wf8 = (unsigned char*)(ws + 65536 + (size_t)N_TOK * DIM);  // 32.77 MB

  hipMemsetAsync(ws, 0, 32768, stream);  // zero rowExp/rowSum (ws poisoned 0xAA)

  tgt_dot<<<N_TOK / 4, 256, 0, stream>>>(x, W, y, tgtRow);

  const int n4x = N_TOK * DIM / 4, n4w = VOCAB * DIM / 4;
  cvt_fp8_2<<<(n4x + n4w + 255) / 256, 256, 0, stream>>>(x, (unsigned int*)Xf8, n4x,
                                                         W, (unsigned int*)Wf8, n4w);

  dim3 grid(N_TOK / BM, VOCAB / BN);  // (32, 250)
  gemm_ce<<<grid, 256, 0, stream>>>(Xf8, Wf8, rowExp, rowSum);

  finalize_kernel<<<1, 256, 0, stream>>>(rowExp, rowSum, tgtRow, out);
}